// Round 5
// baseline (387.202 us; speedup 1.0000x reference)
//
#include <hip/hip_runtime.h>

// y[n,m,:] = x[n,m,:] @ W[l(m)] * (1/sqrt(128))
// x: [100000, 16, 128] f32   W: [4, 128, 128] f32   y: [100000, 16, 128] f32
//
// R4 post-mortem: 2-phase global_load_lds pipeline = 342us (4.8 TB/s), but
// depth-1 prefetch stalls ~700cy/iter at vmcnt (comp ~250cy << HBM ~900cy).
// R5 (T3+T4): prefetch depth 3 over a ring of 4 x 16-row LDS buffers (8KB
// each, 32KB/block -> 4 blocks/CU), derived counted vmcnt
// vm = min(4+2t, 10, 6+2(NT-1-t))  (per-wave issue order: 2 loads + 2 stores
// per iter; steady state waits for loads issued 3 iters ago). Body order:
// vmcnt -> s_barrier -> stage(t+3) -> comp(t); stage-after-barrier is what
// makes overwriting comp(t-1)'s buffer safe. Uniform NT loop, no tail split
// (100000 % 16 == 0). Swizzle unchanged from R4 (rule #21 both-sides:
// pre-swizzled global source slot^=(row&7), linear DMA dest, XOR on ds_read;
// quarter-wave phases give 2 lanes/bank = free).
//
// MFMA: A=W-frag(d), B=x-frag(n), same k->(lanegroup,elem) map both sides so
// the internal K permutation cancels. D: col(lane&15)=n, row((lane>>4)*4+reg)=d
// (HW-verified R1-R4).

typedef __bf16 bf16x8 __attribute__((ext_vector_type(8)));
typedef float f32x4 __attribute__((ext_vector_type(4)));
typedef unsigned short u16x8 __attribute__((ext_vector_type(8)));

#define N_NODES 100000
#define MCOMP 16
#define CIN 128
#define ROWSTRIDE (MCOMP * CIN)  // 2048 floats per node
#define TROWS 16                 // rows per pipeline tile
#define TPB 16                   // tiles per block (256 rows)
#define DEPTH 3                  // prefetch depth (ring of 4 buffers)

__device__ __forceinline__ unsigned short f2b(float f) {
    unsigned int u = __float_as_uint(f);
    unsigned int r = (u + 0x7fffu + ((u >> 16) & 1u)) >> 16;
    return (unsigned short)r;
}

// Wt[l][d][c] = W[l][c][d] * (1/sqrt(128)) as bf16 bits. 128 KiB in d_ws.
__global__ void prep_weights(const float* __restrict__ w,
                             unsigned short* __restrict__ wt) {
    int idx = blockIdx.x * blockDim.x + threadIdx.x;  // 0..65535
    int l = idx >> 14;
    int rem = idx & 16383;
    int d = rem >> 7;
    int c = rem & 127;
    const float pw = 0.08838834764831845f;  // 1/sqrt(128)
    wt[idx] = f2b(w[(l << 14) + (c << 7) + d] * pw);
}

__global__ __launch_bounds__(256, 4) void linear_mfma(
        const float* __restrict__ x,
        const unsigned short* __restrict__ wt,
        float* __restrict__ y) {
    __shared__ float lds[4][TROWS * CIN];  // 4 ring buffers x 8 KiB

    const int m = blockIdx.y;
    const int l = (m >= 9) ? 3 : (m >= 4) ? 2 : (m >= 1) ? 1 : 0;
    const int wid = threadIdx.x >> 6;
    const int lane = threadIdx.x & 63;
    const int lr = lane & 15;   // W-frag d-row / x-frag n / D col (n)
    const int lk = lane >> 4;   // k lane-group
    const int nbase0 = blockIdx.x * (TROWS * TPB);
    const int NT = min(TPB, (N_NODES - nbase0) / TROWS);  // 16, or 10 (tail)

    // W fragments, register-resident: d = wid*32 + df*16 + lr, k = kk*32+lk*8..+8
    const unsigned short* wl = wt + (l << 14);
    bf16x8 wf[2][4];
#pragma unroll
    for (int df = 0; df < 2; ++df)
#pragma unroll
        for (int kk = 0; kk < 4; ++kk)
            wf[df][kk] = __builtin_bit_cast(bf16x8, *(const u16x8*)(
                wl + (((wid * 32 + df * 16 + lr) << 7) + kk * 32 + lk * 8)));

    // stage tile t: 16 rows x 512B into lds[t&3]; 2 x global_load_lds(16B)/wave.
    // LDS linear; global source pre-swizzled slot^=(row&7).
    auto stage = [&](int t) {
        float* buf = lds[t & 3];
        const int hbase = nbase0 + t * TROWS;
#pragma unroll
        for (int j = 0; j < 2; ++j) {
            int seg = wid * 2 + j;               // 1KB segment, wave-uniform
            int row = seg * 2 + (lane >> 5);     // 2 rows per segment
            int slot = (lane & 31) ^ (row & 7);  // 16B slot, pre-swizzled
            const float* src = x + (size_t)(hbase + row) * ROWSTRIDE
                               + m * CIN + slot * 4;
            __builtin_amdgcn_global_load_lds(
                (const __attribute__((address_space(1))) void*)src,
                (__attribute__((address_space(3))) void*)(buf + seg * 256),
                16, 0, 0);
        }
    };

    // compute tile t from lds[t&3] (XOR-deswizzled reads), 8 MFMA, 2 stores.
    auto comp = [&](int t) {
        const float* buf = lds[t & 3];
        f32x4 acc0 = (f32x4){0.f, 0.f, 0.f, 0.f};
        f32x4 acc1 = (f32x4){0.f, 0.f, 0.f, 0.f};
        const int sw = lr & 7;
        const float* rbase = buf + lr * CIN;
#pragma unroll
        for (int kk = 0; kk < 4; ++kk) {
            f32x4 v0 = *(const f32x4*)(rbase + kk * 32 + ((lk * 2) ^ sw) * 4);
            f32x4 v1 = *(const f32x4*)(rbase + kk * 32 + ((lk * 2 + 1) ^ sw) * 4);
            bf16x8 xb;
#pragma unroll
            for (int jj = 0; jj < 4; ++jj) {
                xb[jj] = (__bf16)v0[jj];
                xb[jj + 4] = (__bf16)v1[jj];
            }
            acc0 = __builtin_amdgcn_mfma_f32_16x16x32_bf16(wf[0][kk], xb, acc0, 0, 0, 0);
            acc1 = __builtin_amdgcn_mfma_f32_16x16x32_bf16(wf[1][kk], xb, acc1, 0, 0, 0);
        }
        const int hbase = nbase0 + t * TROWS;
        float* yp = y + (size_t)(hbase + lr) * ROWSTRIDE + m * CIN
                    + wid * 32 + lk * 4;
        *(f32x4*)yp = acc0;
        *(f32x4*)(yp + 16) = acc1;
    };

    // prologue: stage 3 tiles ahead (NT >= 10 always)
    stage(0);
    stage(1);
    stage(2);

    for (int t = 0; t < NT; ++t) {
        // derived wait: own loads for tile t are complete when at most vm
        // newer vmem ops (2 loads + 2 stores per later iter) are outstanding
        int vm = 4 + 2 * t;
        int ve = 6 + 2 * (NT - 1 - t);
        if (ve < vm) vm = ve;
        if (vm > 10) vm = 10;
        switch (vm) {
            case 4:  asm volatile("s_waitcnt vmcnt(4)" ::: "memory"); break;
            case 6:  asm volatile("s_waitcnt vmcnt(6)" ::: "memory"); break;
            case 8:  asm volatile("s_waitcnt vmcnt(8)" ::: "memory"); break;
            default: asm volatile("s_waitcnt vmcnt(10)" ::: "memory"); break;
        }
        __builtin_amdgcn_s_barrier();       // all waves' tile-t loads landed
        __builtin_amdgcn_sched_barrier(0);  // pin phase edge
        if (t + DEPTH < NT) stage(t + DEPTH);  // safe: after barrier, ring slot
                                               // (t+3)&3 == (t-1)&3 is retired
        comp(t);
    }
}

extern "C" void kernel_launch(void* const* d_in, const int* in_sizes, int n_in,
                              void* d_out, int out_size, void* d_ws, size_t ws_size,
                              hipStream_t stream) {
    const float* x = (const float*)d_in[0];
    const float* w = (const float*)d_in[1];
    float* y = (float*)d_out;
    unsigned short* wt = (unsigned short*)d_ws;  // 128 KiB of scratch used

    prep_weights<<<256, 256, 0, stream>>>(w, wt);

    dim3 grid((N_NODES + TROWS * TPB - 1) / (TROWS * TPB), MCOMP);  // 391 x 16
    linear_mfma<<<grid, 256, 0, stream>>>(x, wt, y);
}

// Round 6
// 309.279 us; speedup vs baseline: 1.2520x; 1.2520x over previous
//
#include <hip/hip_runtime.h>

// y[n,m,:] = x[n,m,:] @ W[l(m)] * (1/sqrt(128))
// x: [100000, 16, 128] f32   W: [4, 128, 128] f32   y: [100000, 16, 128] f32
//
// R5 post-mortem: depth-3 prefetch REGRESSED (342->387us) -> R4 was not
// latency-bound; it is BW-efficiency-bound at ~4.7 of ~6.5 TB/s. Revised
// theory: DRAM page locality. x is [n][m][c]; with grid (bx,m) and bx the
// fast dispatch dim, resident blocks share one m -> the machine streams x
// 16 separate times, 512B used per 8KB page per pass (~16x page activations;
// same for y). R6: identical kernel to R4, but grid swapped so m is the FAST
// dimension -> resident blocks = ~64 node-tiles x all 16 m, consuming each
// 8KB node row fully in one sequential sweep (reads and writes).
//
// Kernel structure (R4, unchanged): 2-phase global_load_lds pipeline, two
// 16KB half-buffers (32 rows x 512B), counted s_waitcnt vmcnt(4) + raw
// s_barrier, sched_barrier(0) phase pins. Rule #21 both-sides swizzle:
// pre-swizzled global source (slot^=row&7), linear DMA dest, XOR on ds_read.
// W register-resident per wave. MFMA: A=W-frag(d), B=x-frag(n), same
// k->(lanegroup,elem) map both sides (K-permutation cancels).
// D: col(lane&15)=n, row((lane>>4)*4+reg)=d (HW-verified R1-R5).

typedef __bf16 bf16x8 __attribute__((ext_vector_type(8)));
typedef float f32x4 __attribute__((ext_vector_type(4)));
typedef unsigned short u16x8 __attribute__((ext_vector_type(8)));

#define N_NODES 100000
#define MCOMP 16
#define CIN 128
#define ROWSTRIDE (MCOMP * CIN)  // 2048 floats per node

__device__ __forceinline__ unsigned short f2b(float f) {
    unsigned int u = __float_as_uint(f);
    unsigned int r = (u + 0x7fffu + ((u >> 16) & 1u)) >> 16;
    return (unsigned short)r;
}

// Wt[l][d][c] = W[l][c][d] * (1/sqrt(128)) as bf16 bits. 128 KiB in d_ws.
__global__ void prep_weights(const float* __restrict__ w,
                             unsigned short* __restrict__ wt) {
    int idx = blockIdx.x * blockDim.x + threadIdx.x;  // 0..65535
    int l = idx >> 14;
    int rem = idx & 16383;
    int d = rem >> 7;
    int c = rem & 127;
    const float pw = 0.08838834764831845f;  // 1/sqrt(128)
    wt[idx] = f2b(w[(l << 14) + (c << 7) + d] * pw);
}

__global__ __launch_bounds__(256, 4) void linear_mfma(
        const float* __restrict__ x,
        const unsigned short* __restrict__ wt,
        float* __restrict__ y) {
    __shared__ float lds0[32 * 128];  // 16 KiB half-buffer A
    __shared__ float lds1[32 * 128];  // 16 KiB half-buffer B

    const int m = blockIdx.x;          // FAST dispatch dim: all 16 m adjacent
    const int l = (m >= 9) ? 3 : (m >= 4) ? 2 : (m >= 1) ? 1 : 0;
    const int wid = threadIdx.x >> 6;
    const int lane = threadIdx.x & 63;
    const int lr = lane & 15;   // W-frag d-row / x-frag n / D col (n)
    const int lk = lane >> 4;   // k lane-group
    const int nbase = blockIdx.y * 128;

    // W fragments, register-resident: d = wid*32 + df*16 + lr, k = kk*32+lk*8..+8
    const unsigned short* wl = wt + (l << 14);
    bf16x8 wf[2][4];
#pragma unroll
    for (int df = 0; df < 2; ++df)
#pragma unroll
        for (int kk = 0; kk < 4; ++kk)
            wf[df][kk] = __builtin_bit_cast(bf16x8, *(const u16x8*)(
                wl + (((wid * 32 + df * 16 + lr) << 7) + kk * 32 + lk * 8)));

    // stage half h (rows nbase+h*32 .. +32) into buf: 4 global_load_lds/wave,
    // LDS linear; global source pre-swizzled slot^=(row&7).
    auto stage = [&](float* buf, int h) {
        const int hbase = nbase + h * 32;
#pragma unroll
        for (int j = 0; j < 4; ++j) {
            int seg = wid * 4 + j;                 // 1KB segment, wave-uniform
            int row = seg * 2 + (lane >> 5);       // 2 rows per segment
            int slot = (lane & 31) ^ (row & 7);    // 16B slot, pre-swizzled
            const float* src = x + (size_t)(hbase + row) * ROWSTRIDE
                               + m * CIN + slot * 4;
            __builtin_amdgcn_global_load_lds(
                (const __attribute__((address_space(1))) void*)src,
                (__attribute__((address_space(3))) void*)(buf + seg * 256),
                16, 0, 0);
        }
    };

    // compute half h from buf (ds_read XOR-deswizzled), MFMA, store to y.
    // Exactly 4 vmem stores per wave (counted in the vmcnt discipline).
    auto comp = [&](const float* buf, int h) {
        f32x4 acc[2][2];
#pragma unroll
        for (int rf = 0; rf < 2; ++rf)
#pragma unroll
            for (int df = 0; df < 2; ++df)
                acc[rf][df] = (f32x4){0.f, 0.f, 0.f, 0.f};

#pragma unroll
        for (int kk = 0; kk < 4; ++kk) {
#pragma unroll
            for (int rf = 0; rf < 2; ++rf) {
                int row = rf * 16 + lr;
                int sw = row & 7;
                const float* rbase = buf + row * 128 + kk * 32;
                f32x4 v0 = *(const f32x4*)(rbase + ((lk * 2) ^ sw) * 4);
                f32x4 v1 = *(const f32x4*)(rbase + ((lk * 2 + 1) ^ sw) * 4);
                bf16x8 xb;
#pragma unroll
                for (int jj = 0; jj < 4; ++jj) {
                    xb[jj] = (__bf16)v0[jj];
                    xb[jj + 4] = (__bf16)v1[jj];
                }
                acc[rf][0] = __builtin_amdgcn_mfma_f32_16x16x32_bf16(
                    wf[0][kk], xb, acc[rf][0], 0, 0, 0);
                acc[rf][1] = __builtin_amdgcn_mfma_f32_16x16x32_bf16(
                    wf[1][kk], xb, acc[rf][1], 0, 0, 0);
            }
        }
        const int hbase = nbase + h * 32;
#pragma unroll
        for (int rf = 0; rf < 2; ++rf)
#pragma unroll
            for (int df = 0; df < 2; ++df) {
                float* yp = y + (size_t)(hbase + rf * 16 + lr) * ROWSTRIDE
                            + m * CIN + wid * 32 + df * 16 + lk * 4;
                *(f32x4*)yp = acc[rf][df];
            }
    };

    if (nbase + 128 <= N_NODES) {
        // steady schedule: stage(t+1); comp(t); vmcnt(4); barrier
        stage(lds0, 0);
        asm volatile("s_waitcnt vmcnt(0)" ::: "memory");
        __builtin_amdgcn_s_barrier();

        stage(lds1, 1);
        __builtin_amdgcn_sched_barrier(0);
        comp(lds0, 0);
        asm volatile("s_waitcnt vmcnt(4)" ::: "memory");
        __builtin_amdgcn_s_barrier();

        stage(lds0, 2);
        __builtin_amdgcn_sched_barrier(0);
        comp(lds1, 1);
        asm volatile("s_waitcnt vmcnt(4)" ::: "memory");
        __builtin_amdgcn_s_barrier();

        stage(lds1, 3);
        __builtin_amdgcn_sched_barrier(0);
        comp(lds0, 2);
        asm volatile("s_waitcnt vmcnt(4)" ::: "memory");
        __builtin_amdgcn_s_barrier();

        comp(lds1, 3);
    } else {
        // tail block: exactly 32 rows (100000 % 128 == 32), one half
        stage(lds0, 0);
        asm volatile("s_waitcnt vmcnt(0)" ::: "memory");
        __builtin_amdgcn_s_barrier();
        comp(lds0, 0);
    }
}

extern "C" void kernel_launch(void* const* d_in, const int* in_sizes, int n_in,
                              void* d_out, int out_size, void* d_ws, size_t ws_size,
                              hipStream_t stream) {
    const float* x = (const float*)d_in[0];
    const float* w = (const float*)d_in[1];
    float* y = (float*)d_out;
    unsigned short* wt = (unsigned short*)d_ws;  // 128 KiB of scratch used

    prep_weights<<<256, 256, 0, stream>>>(w, wt);

    // m fast, node-tile slow: resident blocks cover all 16 m of consecutive
    // node tiles -> one sequential HBM sweep instead of 16 striped passes.
    dim3 grid(MCOMP, (N_NODES + 127) / 128);  // 16 x 782
    linear_mfma<<<grid, 256, 0, stream>>>(x, wt, y);
}